// Round 1
// baseline (4140.803 us; speedup 1.0000x reference)
//
#include <hip/hip_runtime.h>

// Problem constants (fixed by the reference)
#define Bb  2
#define Ss  2048
#define Dd  2048
#define HKV 8
#define QPK 4
#define HD  64
#define MR  (Bb * Ss)   // 4096 rows of "tokens"
#define NQ  2048        // HQ*HD
#define NKV 512         // HKV*HD

typedef unsigned short u16;
typedef __attribute__((ext_vector_type(8))) short s16x8;   // 8 x bf16 (4 VGPRs)
typedef __attribute__((ext_vector_type(4))) float f32x4;   // MFMA accumulator

__device__ __forceinline__ u16 f2bf(float f) {
  unsigned u = __float_as_uint(f);
  u += 0x7fffu + ((u >> 16) & 1u);   // RNE; inputs are finite
  return (u16)(u >> 16);
}

// ---------------------------------------------------------------------------
// LayerNorm: one block per row (4096 rows, D=2048), fp32 in -> bf16 out
// ---------------------------------------------------------------------------
__global__ __launch_bounds__(256) void ln_kernel(
    const float* __restrict__ x, const float* __restrict__ g,
    const float* __restrict__ be, u16* __restrict__ xn)
{
  int row = blockIdx.x;
  int tid = threadIdx.x;
  const float4* xr = (const float4*)(x + (size_t)row * Dd);
  float4 a = xr[tid];
  float4 b4 = xr[tid + 256];
  float s  = a.x + a.y + a.z + a.w + b4.x + b4.y + b4.z + b4.w;
  float ss = a.x*a.x + a.y*a.y + a.z*a.z + a.w*a.w
           + b4.x*b4.x + b4.y*b4.y + b4.z*b4.z + b4.w*b4.w;
  #pragma unroll
  for (int off = 32; off > 0; off >>= 1) {
    s  += __shfl_down(s, off);
    ss += __shfl_down(ss, off);
  }
  __shared__ float red[8];
  int lane = tid & 63, w = tid >> 6;
  if (lane == 0) { red[w] = s; red[4 + w] = ss; }
  __syncthreads();
  s  = red[0] + red[1] + red[2] + red[3];
  ss = red[4] + red[5] + red[6] + red[7];
  float mu = s * (1.0f / Dd);
  float rs = rsqrtf(ss * (1.0f / Dd) - mu * mu + 1e-5f);

  u16* xo = xn + (size_t)row * Dd;
  const float4* gv4 = (const float4*)g;
  const float4* bv4 = (const float4*)be;
  #pragma unroll
  for (int p = 0; p < 2; ++p) {
    int idx = tid + p * 256;
    float4 xv = (p == 0) ? a : b4;
    float4 gg = gv4[idx], bb = bv4[idx];
    ushort4 pk;
    pk.x = f2bf((xv.x - mu) * rs * gg.x + bb.x);
    pk.y = f2bf((xv.y - mu) * rs * gg.y + bb.y);
    pk.z = f2bf((xv.z - mu) * rs * gg.z + bb.z);
    pk.w = f2bf((xv.w - mu) * rs * gg.w + bb.w);
    *(ushort4*)(xo + idx * 4) = pk;
  }
}

// ---------------------------------------------------------------------------
// Weight transpose + cast: W (K x N) fp32 -> WT (N x K) bf16, 32x32 LDS tiles
// ---------------------------------------------------------------------------
__global__ __launch_bounds__(256) void transpose_cast(
    const float* __restrict__ W, u16* __restrict__ WT, int K, int N)
{
  __shared__ float tile[32][33];
  int tx = threadIdx.x & 31, ty = threadIdx.x >> 5;  // ty 0..7
  int n0 = blockIdx.x * 32, k0 = blockIdx.y * 32;
  #pragma unroll
  for (int i = 0; i < 4; ++i)
    tile[ty + 8 * i][tx] = W[(size_t)(k0 + ty + 8 * i) * N + n0 + tx];
  __syncthreads();
  #pragma unroll
  for (int i = 0; i < 4; ++i)
    WT[(size_t)(n0 + ty + 8 * i) * K + k0 + tx] = f2bf(tile[tx][ty + 8 * i]);
}

// ---------------------------------------------------------------------------
// bf16 MFMA GEMM: C(M,N) fp32 = (A(M,K)bf16 @ BT(N,K)bf16^T + bias) * scale
// 128x128 tile, BK=32, 4 waves each computing 64x64 (4x4 MFMA 16x16x32 tiles)
// M,N,K must be multiples of 128/128/32 (all shapes here qualify)
// ---------------------------------------------------------------------------
__global__ __launch_bounds__(256) void gemm_bt(
    const u16* __restrict__ A, const u16* __restrict__ BT,
    const float* __restrict__ bias, float* __restrict__ C,
    int M, int N, int K, float scale)
{
  __shared__ u16 As[128][40];   // +8 pad: 80B row stride, 16B aligned
  __shared__ u16 Bs[128][40];
  int tid  = threadIdx.x;
  int lane = tid & 63, wave = tid >> 6;
  int wm = (wave >> 1) * 64, wn = (wave & 1) * 64;
  int m16 = lane & 15, quad = lane >> 4;
  int ar = tid >> 2;            // 0..63 (staging row; +64 for second row)
  int ac = (tid & 3) * 8;       // 0,8,16,24 (staging col, 8 bf16 = 16B)
  const u16* Ag = A  + (size_t)(blockIdx.y * 128 + ar) * K + ac;
  const u16* Bg = BT + (size_t)(blockIdx.x * 128 + ar) * K + ac;

  f32x4 acc[4][4] = {};
  for (int k0 = 0; k0 < K; k0 += 32) {
    int4 a0 = *(const int4*)(Ag + k0);
    int4 a1 = *(const int4*)(Ag + (size_t)64 * K + k0);
    int4 b0 = *(const int4*)(Bg + k0);
    int4 b1 = *(const int4*)(Bg + (size_t)64 * K + k0);
    __syncthreads();
    *(int4*)&As[ar][ac]      = a0;
    *(int4*)&As[ar + 64][ac] = a1;
    *(int4*)&Bs[ar][ac]      = b0;
    *(int4*)&Bs[ar + 64][ac] = b1;
    __syncthreads();
    s16x8 af[4], bf[4];
    #pragma unroll
    for (int i = 0; i < 4; ++i)
      af[i] = *(const s16x8*)&As[wm + i * 16 + m16][quad * 8];
    #pragma unroll
    for (int j = 0; j < 4; ++j)
      bf[j] = *(const s16x8*)&Bs[wn + j * 16 + m16][quad * 8];
    #pragma unroll
    for (int i = 0; i < 4; ++i)
      #pragma unroll
      for (int j = 0; j < 4; ++j)
        acc[i][j] = __builtin_amdgcn_mfma_f32_16x16x32_bf16(af[i], bf[j], acc[i][j], 0, 0, 0);
  }
  // epilogue: C/D layout col=lane&15, row=quad*4+reg (verified m89/m91)
  #pragma unroll
  for (int i = 0; i < 4; ++i) {
    #pragma unroll
    for (int j = 0; j < 4; ++j) {
      int col = blockIdx.x * 128 + wn + j * 16 + m16;
      float bcol = bias[col];
      #pragma unroll
      for (int r = 0; r < 4; ++r) {
        int rowg = blockIdx.y * 128 + wm + i * 16 + quad * 4 + r;
        C[(size_t)rowg * N + col] = (acc[i][j][r] + bcol) * scale;
      }
    }
  }
}

// ---------------------------------------------------------------------------
// Pass A: per-column softmax stats.  softmax is over the QUERY axis t (the
// reference's axis=1), so for each (b,h,qk,T): m = max_{t>=T} s(t,T),
// l = sum_{t>=T} exp(s-m).  Thread owns one column T; k-row in registers;
// q rows are block-uniform (scalar loads).
// ---------------------------------------------------------------------------
__global__ __launch_bounds__(256) void pass_a(
    const float* __restrict__ q, const float* __restrict__ k,
    float2* __restrict__ ml)
{
  int bh = blockIdx.z;               // b*8 + h
  int b = bh >> 3, h = bh & 7;
  int qk = blockIdx.y;               // 0..3
  int T = blockIdx.x * 256 + threadIdx.x;

  const float* kp = k + ((size_t)(b * Ss + T)) * NKV + h * HD;
  float kr[64];
  #pragma unroll
  for (int i = 0; i < 16; ++i) {
    float4 t4 = *(const float4*)(kp + 4 * i);
    kr[4*i] = t4.x; kr[4*i+1] = t4.y; kr[4*i+2] = t4.z; kr[4*i+3] = t4.w;
  }
  const float* qb = q + (size_t)b * Ss * NQ + h * (QPK * HD) + qk * HD;
  float m = -1e30f, l = 0.f;
  int t0 = blockIdx.x * 256;
  for (int t = t0; t < Ss; ++t) {
    const float4* qp = (const float4*)(qb + (size_t)t * NQ);
    float s0 = 0, s1 = 0, s2 = 0, s3 = 0;
    #pragma unroll
    for (int i = 0; i < 16; ++i) {
      float4 qv = qp[i];
      s0 = fmaf(qv.x, kr[4*i+0], s0);
      s1 = fmaf(qv.y, kr[4*i+1], s1);
      s2 = fmaf(qv.z, kr[4*i+2], s2);
      s3 = fmaf(qv.w, kr[4*i+3], s3);
    }
    float sv = (s0 + s1) + (s2 + s3);
    if (t >= T) {
      float mn = fmaxf(m, sv);
      l = l * __expf(m - mn) + __expf(sv - mn);
      m = mn;
    }
  }
  ml[((size_t)bh * Ss + T) * QPK + qk] = make_float2(m, 1.0f / l);
}

// ---------------------------------------------------------------------------
// Pass B: out[t,h,qk,:] = sum_{T<=t} exp(s(t,T)-m[T]) * (1/l[T]) * v[T,:]
// Thread owns one (t,qk) row: q-row + 64-wide out accumulator in registers;
// k/v rows and stats are block-uniform loads.  Writes attn in bf16.
// ---------------------------------------------------------------------------
__global__ __launch_bounds__(256) void pass_b(
    const float* __restrict__ q, const float* __restrict__ k,
    const float* __restrict__ v, const float2* __restrict__ ml,
    u16* __restrict__ attn)
{
  int bh = blockIdx.y;
  int b = bh >> 3, h = bh & 7;
  int t  = blockIdx.x * 64 + (threadIdx.x >> 2);
  int qk = threadIdx.x & 3;

  const float* qp = q + ((size_t)(b * Ss + t)) * NQ + h * (QPK * HD) + qk * HD;
  float qr[64];
  #pragma unroll
  for (int i = 0; i < 16; ++i) {
    float4 t4 = *(const float4*)(qp + 4 * i);
    qr[4*i] = t4.x; qr[4*i+1] = t4.y; qr[4*i+2] = t4.z; qr[4*i+3] = t4.w;
  }
  float out[64];
  #pragma unroll
  for (int i = 0; i < 64; ++i) out[i] = 0.f;

  const float* kb = k + (size_t)b * Ss * NKV + h * HD;
  const float* vb = v + (size_t)b * Ss * NKV + h * HD;
  const float2* mlb = ml + (size_t)bh * Ss * QPK + qk;
  int tEnd = blockIdx.x * 64 + 63;

  for (int T = 0; T <= tEnd; ++T) {
    const float4* kp4 = (const float4*)(kb + (size_t)T * NKV);
    float s0 = 0, s1 = 0, s2 = 0, s3 = 0;
    #pragma unroll
    for (int i = 0; i < 16; ++i) {
      float4 kv = kp4[i];
      s0 = fmaf(qr[4*i+0], kv.x, s0);
      s1 = fmaf(qr[4*i+1], kv.y, s1);
      s2 = fmaf(qr[4*i+2], kv.z, s2);
      s3 = fmaf(qr[4*i+3], kv.w, s3);
    }
    float sv = (s0 + s1) + (s2 + s3);
    float2 mr = mlb[(size_t)T * QPK];
    float e = (T <= t) ? __expf(sv - mr.x) * mr.y : 0.f;
    const float4* vp4 = (const float4*)(vb + (size_t)T * NKV);
    #pragma unroll
    for (int i = 0; i < 16; ++i) {
      float4 vv = vp4[i];
      out[4*i+0] = fmaf(e, vv.x, out[4*i+0]);
      out[4*i+1] = fmaf(e, vv.y, out[4*i+1]);
      out[4*i+2] = fmaf(e, vv.z, out[4*i+2]);
      out[4*i+3] = fmaf(e, vv.w, out[4*i+3]);
    }
  }
  u16* ap = attn + ((size_t)(b * Ss + t)) * NQ + h * (QPK * HD) + qk * HD;
  #pragma unroll
  for (int i = 0; i < 16; ++i) {
    ushort4 pk;
    pk.x = f2bf(out[4*i+0]); pk.y = f2bf(out[4*i+1]);
    pk.z = f2bf(out[4*i+2]); pk.w = f2bf(out[4*i+3]);
    *(ushort4*)(ap + 4 * i) = pk;
  }
}

// ---------------------------------------------------------------------------
extern "C" void kernel_launch(void* const* d_in, const int* in_sizes, int n_in,
                              void* d_out, int out_size, void* d_ws, size_t ws_size,
                              hipStream_t stream)
{
  (void)in_sizes; (void)n_in; (void)out_size; (void)ws_size;
  const float* x   = (const float*)d_in[0];
  const float* lng = (const float*)d_in[1];
  const float* lnb = (const float*)d_in[2];
  const float* Wq  = (const float*)d_in[3];
  const float* bq  = (const float*)d_in[4];
  const float* Wk  = (const float*)d_in[5];
  const float* bk  = (const float*)d_in[6];
  const float* Wv  = (const float*)d_in[7];
  const float* bv  = (const float*)d_in[8];
  const float* Wo  = (const float*)d_in[9];
  const float* bo  = (const float*)d_in[10];
  float* out = (float*)d_out;

  char* ws = (char*)d_ws;
  size_t off = 0;
  auto take = [&](size_t bytes) -> char* {
    char* p = ws + off;
    off += (bytes + 255) & ~(size_t)255;
    return p;
  };
  u16*    xnb   = (u16*)take((size_t)MR * Dd * 2);          // 16 MB
  u16*    wqT   = (u16*)take((size_t)NQ * Dd * 2);          // 8 MB
  u16*    wkT   = (u16*)take((size_t)NKV * Dd * 2);         // 2 MB
  u16*    wvT   = (u16*)take((size_t)NKV * Dd * 2);         // 2 MB
  u16*    woT   = (u16*)take((size_t)Dd * NQ * 2);          // 8 MB
  float*  qf    = (float*)take((size_t)MR * NQ * 4);        // 32 MB
  float*  kf    = (float*)take((size_t)MR * NKV * 4);       // 8 MB
  float*  vf    = (float*)take((size_t)MR * NKV * 4);       // 8 MB
  float2* ml    = (float2*)take((size_t)Bb * HKV * Ss * QPK * 8); // 1 MB
  u16*    attnb = (u16*)take((size_t)MR * NQ * 2);          // 16 MB
  // total ~101 MB of d_ws

  ln_kernel<<<MR, 256, 0, stream>>>(x, lng, lnb, xnb);
  transpose_cast<<<dim3(NQ / 32, Dd / 32), 256, 0, stream>>>(Wq, wqT, Dd, NQ);
  transpose_cast<<<dim3(NKV / 32, Dd / 32), 256, 0, stream>>>(Wk, wkT, Dd, NKV);
  transpose_cast<<<dim3(NKV / 32, Dd / 32), 256, 0, stream>>>(Wv, wvT, Dd, NKV);
  transpose_cast<<<dim3(NQ / 32, Dd / 32), 256, 0, stream>>>(Wo, woT, Dd, NQ);

  gemm_bt<<<dim3(NQ / 128, MR / 128), 256, 0, stream>>>(xnb, wqT, bq, qf, MR, NQ, Dd, 0.125f);
  gemm_bt<<<dim3(NKV / 128, MR / 128), 256, 0, stream>>>(xnb, wkT, bk, kf, MR, NKV, Dd, 1.0f);
  gemm_bt<<<dim3(NKV / 128, MR / 128), 256, 0, stream>>>(xnb, wvT, bv, vf, MR, NKV, Dd, 1.0f);

  pass_a<<<dim3(Ss / 256, QPK, Bb * HKV), 256, 0, stream>>>(qf, kf, ml);
  pass_b<<<dim3(Ss / 64, Bb * HKV), 256, 0, stream>>>(qf, kf, vf, ml, attnb);

  gemm_bt<<<dim3(Dd / 128, MR / 128), 256, 0, stream>>>(attnb, woT, bo, out, MR, Dd, NQ, 1.0f);
}

// Round 2
// 611.236 us; speedup vs baseline: 6.7745x; 6.7745x over previous
//
#include <hip/hip_runtime.h>

// Problem constants (fixed by the reference)
#define Bb  2
#define Ss  2048
#define Dd  2048
#define HKV 8
#define QPK 4
#define HD  64
#define MR  (Bb * Ss)   // 4096 token rows
#define NQ  2048        // HQ*HD
#define NKV 512         // HKV*HD

typedef unsigned short u16;
typedef __attribute__((ext_vector_type(8))) short s16x8;   // 8 x bf16 (4 VGPRs)
typedef __attribute__((ext_vector_type(4))) float f32x4;   // MFMA accumulator

__device__ __forceinline__ u16 f2bf(float f) {
  unsigned u = __float_as_uint(f);
  u += 0x7fffu + ((u >> 16) & 1u);   // RNE; inputs finite
  return (u16)(u >> 16);
}

// ---------------------------------------------------------------------------
// LayerNorm: one block per row, fp32 in -> bf16 out
// ---------------------------------------------------------------------------
__global__ __launch_bounds__(256) void ln_kernel(
    const float* __restrict__ x, const float* __restrict__ g,
    const float* __restrict__ be, u16* __restrict__ xn)
{
  int row = blockIdx.x;
  int tid = threadIdx.x;
  const float4* xr = (const float4*)(x + (size_t)row * Dd);
  float4 a = xr[tid];
  float4 b4 = xr[tid + 256];
  float s  = a.x + a.y + a.z + a.w + b4.x + b4.y + b4.z + b4.w;
  float ss = a.x*a.x + a.y*a.y + a.z*a.z + a.w*a.w
           + b4.x*b4.x + b4.y*b4.y + b4.z*b4.z + b4.w*b4.w;
  #pragma unroll
  for (int off = 32; off > 0; off >>= 1) {
    s  += __shfl_down(s, off);
    ss += __shfl_down(ss, off);
  }
  __shared__ float red[8];
  int lane = tid & 63, w = tid >> 6;
  if (lane == 0) { red[w] = s; red[4 + w] = ss; }
  __syncthreads();
  s  = red[0] + red[1] + red[2] + red[3];
  ss = red[4] + red[5] + red[6] + red[7];
  float mu = s * (1.0f / Dd);
  float rs = rsqrtf(ss * (1.0f / Dd) - mu * mu + 1e-5f);

  u16* xo = xn + (size_t)row * Dd;
  const float4* gv4 = (const float4*)g;
  const float4* bv4 = (const float4*)be;
  #pragma unroll
  for (int p = 0; p < 2; ++p) {
    int idx = tid + p * 256;
    float4 xv = (p == 0) ? a : b4;
    float4 gg = gv4[idx], bb = bv4[idx];
    ushort4 pk;
    pk.x = f2bf((xv.x - mu) * rs * gg.x + bb.x);
    pk.y = f2bf((xv.y - mu) * rs * gg.y + bb.y);
    pk.z = f2bf((xv.z - mu) * rs * gg.z + bb.z);
    pk.w = f2bf((xv.w - mu) * rs * gg.w + bb.w);
    *(ushort4*)(xo + idx * 4) = pk;
  }
}

// ---------------------------------------------------------------------------
// Weight transpose + cast: W (K x N) fp32 -> WT (N x K) bf16
// ---------------------------------------------------------------------------
__global__ __launch_bounds__(256) void transpose_cast(
    const float* __restrict__ W, u16* __restrict__ WT, int K, int N)
{
  __shared__ float tile[32][33];
  int tx = threadIdx.x & 31, ty = threadIdx.x >> 5;  // ty 0..7
  int n0 = blockIdx.x * 32, k0 = blockIdx.y * 32;
  #pragma unroll
  for (int i = 0; i < 4; ++i)
    tile[ty + 8 * i][tx] = W[(size_t)(k0 + ty + 8 * i) * N + n0 + tx];
  __syncthreads();
  #pragma unroll
  for (int i = 0; i < 4; ++i)
    WT[(size_t)(n0 + ty + 8 * i) * K + k0 + tx] = f2bf(tile[tx][ty + 8 * i]);
}

// ---------------------------------------------------------------------------
// V transpose: vb (b,t, h*64+d) bf16 -> vT (b*512 + h*64+d, t) bf16
// ---------------------------------------------------------------------------
__global__ __launch_bounds__(256) void transpose_v(
    const u16* __restrict__ vb, u16* __restrict__ vT)
{
  __shared__ u16 tile[32][33];
  int tx = threadIdx.x & 31, ty = threadIdx.x >> 5;
  int c0 = blockIdx.x * 32;     // 0..511  (h*64+d)
  int r0 = blockIdx.y * 32;     // 0..4095 (b*2048+t), tiles never cross b
  #pragma unroll
  for (int i = 0; i < 4; ++i)
    tile[ty + 8 * i][tx] = vb[(size_t)(r0 + ty + 8 * i) * NKV + c0 + tx];
  __syncthreads();
  int b = r0 >> 11, t = r0 & 2047;
  #pragma unroll
  for (int i = 0; i < 4; ++i)
    vT[((size_t)(b * NKV + c0 + ty + 8 * i)) * Ss + t + tx] = tile[tx][ty + 8 * i];
}

// ---------------------------------------------------------------------------
// bf16 MFMA GEMM: C(M,N) = (A(M,K)bf16 @ BT(N,K)^T + bias) * scale
// 128x128 tile, BK=32; output fp32 or bf16
// ---------------------------------------------------------------------------
template<bool BF16OUT>
__global__ __launch_bounds__(256) void gemm_bt(
    const u16* __restrict__ A, const u16* __restrict__ BT,
    const float* __restrict__ bias, void* __restrict__ Cv,
    int M, int N, int K, float scale)
{
  __shared__ u16 As[128][40];
  __shared__ u16 Bs[128][40];
  int tid  = threadIdx.x;
  int lane = tid & 63, wave = tid >> 6;
  int wm = (wave >> 1) * 64, wn = (wave & 1) * 64;
  int m16 = lane & 15, quad = lane >> 4;
  int ar = tid >> 2;
  int ac = (tid & 3) * 8;
  const u16* Ag = A  + (size_t)(blockIdx.y * 128 + ar) * K + ac;
  const u16* Bg = BT + (size_t)(blockIdx.x * 128 + ar) * K + ac;

  f32x4 acc[4][4] = {};
  for (int k0 = 0; k0 < K; k0 += 32) {
    int4 a0 = *(const int4*)(Ag + k0);
    int4 a1 = *(const int4*)(Ag + (size_t)64 * K + k0);
    int4 b0 = *(const int4*)(Bg + k0);
    int4 b1 = *(const int4*)(Bg + (size_t)64 * K + k0);
    __syncthreads();
    *(int4*)&As[ar][ac]      = a0;
    *(int4*)&As[ar + 64][ac] = a1;
    *(int4*)&Bs[ar][ac]      = b0;
    *(int4*)&Bs[ar + 64][ac] = b1;
    __syncthreads();
    s16x8 af[4], bf[4];
    #pragma unroll
    for (int i = 0; i < 4; ++i)
      af[i] = *(const s16x8*)&As[wm + i * 16 + m16][quad * 8];
    #pragma unroll
    for (int j = 0; j < 4; ++j)
      bf[j] = *(const s16x8*)&Bs[wn + j * 16 + m16][quad * 8];
    #pragma unroll
    for (int i = 0; i < 4; ++i)
      #pragma unroll
      for (int j = 0; j < 4; ++j)
        acc[i][j] = __builtin_amdgcn_mfma_f32_16x16x32_bf16(af[i], bf[j], acc[i][j], 0, 0, 0);
  }
  #pragma unroll
  for (int i = 0; i < 4; ++i) {
    #pragma unroll
    for (int j = 0; j < 4; ++j) {
      int col = blockIdx.x * 128 + wn + j * 16 + m16;
      float bcol = bias[col];
      #pragma unroll
      for (int r = 0; r < 4; ++r) {
        int rowg = blockIdx.y * 128 + wm + i * 16 + quad * 4 + r;
        float val = (acc[i][j][r] + bcol) * scale;
        if constexpr (BF16OUT)
          ((u16*)Cv)[(size_t)rowg * N + col] = f2bf(val);
        else
          ((float*)Cv)[(size_t)rowg * N + col] = val;
      }
    }
  }
}

// ---------------------------------------------------------------------------
// Pass A (MFMA): per-column softmax stats over the QUERY axis t.
// Wave owns 64 T-columns (K-frags preloaded); streams t-blocks of 64.
// C-layout: row(t) = quad*4+r (+i*16), col(T) = lane&15 (+j*16).
// ---------------------------------------------------------------------------
__global__ __launch_bounds__(256) void pass_a_mfma(
    const u16* __restrict__ qb, const u16* __restrict__ kb,
    float2* __restrict__ ml)
{
  int bh = blockIdx.z, b = bh >> 3, h = bh & 7;
  int qk = blockIdx.y;
  int lane = threadIdx.x & 63, wave = threadIdx.x >> 6;
  int m16 = lane & 15, quad = lane >> 4;
  int T0 = blockIdx.x * 256 + wave * 64;

  const u16* kbase = kb + (size_t)b * Ss * NKV + h * HD;
  const u16* qbase = qb + (size_t)b * Ss * NQ + (h * QPK + qk) * HD;

  s16x8 bkf[4][2];
  #pragma unroll
  for (int j = 0; j < 4; ++j)
    #pragma unroll
    for (int kh = 0; kh < 2; ++kh)
      bkf[j][kh] = *(const s16x8*)(kbase + (size_t)(T0 + j * 16 + m16) * NKV + kh * 32 + quad * 8);

  float mcol[4] = {-1e30f, -1e30f, -1e30f, -1e30f};
  float lcol[4] = {0.f, 0.f, 0.f, 0.f};

  for (int t0 = T0; t0 < Ss; t0 += 64) {
    s16x8 af[4][2];
    #pragma unroll
    for (int i = 0; i < 4; ++i) {
      af[i][0] = *(const s16x8*)(qbase + (size_t)(t0 + i * 16 + m16) * NQ + quad * 8);
      af[i][1] = *(const s16x8*)(qbase + (size_t)(t0 + i * 16 + m16) * NQ + 32 + quad * 8);
    }
    f32x4 sa[4][4];
    #pragma unroll
    for (int i = 0; i < 4; ++i)
      #pragma unroll
      for (int j = 0; j < 4; ++j) {
        f32x4 z = {};
        z = __builtin_amdgcn_mfma_f32_16x16x32_bf16(af[i][0], bkf[j][0], z, 0, 0, 0);
        sa[i][j] = __builtin_amdgcn_mfma_f32_16x16x32_bf16(af[i][1], bkf[j][1], z, 0, 0, 0);
      }
    if (t0 == T0) {   // diagonal block: mask t < T (sentinel; col max stays real via diag elem)
      #pragma unroll
      for (int i = 0; i < 4; ++i)
        #pragma unroll
        for (int j = 0; j < 4; ++j) {
          int tg = t0 + i * 16 + quad * 4;
          int Tg = T0 + j * 16 + m16;
          #pragma unroll
          for (int r = 0; r < 4; ++r)
            if (tg + r < Tg) sa[i][j][r] = -1e30f;
        }
    }
    #pragma unroll
    for (int j = 0; j < 4; ++j) {
      float mv = -1e30f;
      #pragma unroll
      for (int i = 0; i < 4; ++i)
        #pragma unroll
        for (int r = 0; r < 4; ++r) mv = fmaxf(mv, sa[i][j][r]);
      mv = fmaxf(mv, __shfl_xor(mv, 16));
      mv = fmaxf(mv, __shfl_xor(mv, 32));
      float mn = fmaxf(mcol[j], mv);
      float se = 0.f;
      #pragma unroll
      for (int i = 0; i < 4; ++i)
        #pragma unroll
        for (int r = 0; r < 4; ++r) se += __expf(sa[i][j][r] - mn);
      se += __shfl_xor(se, 16);
      se += __shfl_xor(se, 32);
      lcol[j] = lcol[j] * __expf(mcol[j] - mn) + se;
      mcol[j] = mn;
    }
  }
  if (quad == 0) {
    float2* mlb = ml + (size_t)(bh * QPK + qk) * Ss;
    #pragma unroll
    for (int j = 0; j < 4; ++j)
      mlb[T0 + j * 16 + m16] = make_float2(mcol[j], 1.0f / lcol[j]);
  }
}

// ---------------------------------------------------------------------------
// Pass B (MFMA): out[t,:] = sum_{T<=t} exp(s(t,T)-m[T])*linv[T] * v[T,:]
// Wave owns 64 t-rows (Q-frags preloaded).  Per T-block: S^T via MFMA
// (rows=T on quad axis -> 4 consecutive T per lane), exp+normalize, pack
// bf16 -> LDS (row-major t x T, +8 pad), re-read as A-frags, PV MFMA.
// ---------------------------------------------------------------------------
__global__ __launch_bounds__(256) void pass_b_mfma(
    const u16* __restrict__ qb, const u16* __restrict__ kb,
    const u16* __restrict__ vT, const float2* __restrict__ ml,
    u16* __restrict__ attn)
{
  __shared__ u16 P[4][64][72];   // per-wave 64t x 64T (+8 pad), 36 KB
  int bh = blockIdx.z, b = bh >> 3, h = bh & 7;
  int qk = blockIdx.y;
  int lane = threadIdx.x & 63, wave = threadIdx.x >> 6;
  int m16 = lane & 15, quad = lane >> 4;
  int t0w = blockIdx.x * 256 + wave * 64;

  const u16* kbase = kb + (size_t)b * Ss * NKV + h * HD;
  const u16* qbase = qb + (size_t)b * Ss * NQ + (h * QPK + qk) * HD;
  const u16* vbase = vT + (size_t)(bh * 64) * Ss;
  const float2* mlb = ml + (size_t)(bh * QPK + qk) * Ss;

  s16x8 qf[4][2];
  #pragma unroll
  for (int tj = 0; tj < 4; ++tj)
    #pragma unroll
    for (int kh = 0; kh < 2; ++kh)
      qf[tj][kh] = *(const s16x8*)(qbase + (size_t)(t0w + tj * 16 + m16) * NQ + kh * 32 + quad * 8);

  f32x4 oacc[4][4] = {};   // [t-tile][d-tile], C-layout rows t, cols d

  for (int T0 = 0; T0 <= t0w; T0 += 64) {
    bool diag = (T0 == t0w);
    // ---- scores S^T (m=T, n=t), exp-normalize, stage P to LDS ----
    #pragma unroll 1
    for (int i = 0; i < 4; ++i) {     // T-subtiles of 16
      s16x8 af0 = *(const s16x8*)(kbase + (size_t)(T0 + i * 16 + m16) * NKV + quad * 8);
      s16x8 af1 = *(const s16x8*)(kbase + (size_t)(T0 + i * 16 + m16) * NKV + 32 + quad * 8);
      f32x4 sacc[4];
      #pragma unroll
      for (int tj = 0; tj < 4; ++tj) {
        f32x4 z = {};
        z = __builtin_amdgcn_mfma_f32_16x16x32_bf16(af0, qf[tj][0], z, 0, 0, 0);
        sacc[tj] = __builtin_amdgcn_mfma_f32_16x16x32_bf16(af1, qf[tj][1], sacc[tj] = z, 0, 0, 0);
      }
      const float4* mp = (const float4*)(mlb + T0 + i * 16 + quad * 4);
      float4 p0 = mp[0], p1 = mp[1];   // (m0,li0,m1,li1),(m2,li2,m3,li3)
      #pragma unroll
      for (int tj = 0; tj < 4; ++tj) {
        float e0 = __expf(sacc[tj][0] - p0.x) * p0.y;
        float e1 = __expf(sacc[tj][1] - p0.z) * p0.w;
        float e2 = __expf(sacc[tj][2] - p1.x) * p1.y;
        float e3 = __expf(sacc[tj][3] - p1.z) * p1.w;
        if (diag) {
          int tg  = t0w + tj * 16 + m16;
          int Tg0 = T0 + i * 16 + quad * 4;
          if (Tg0 + 0 > tg) e0 = 0.f;
          if (Tg0 + 1 > tg) e1 = 0.f;
          if (Tg0 + 2 > tg) e2 = 0.f;
          if (Tg0 + 3 > tg) e3 = 0.f;
        }
        unsigned lo = (unsigned)f2bf(e0) | ((unsigned)f2bf(e1) << 16);
        unsigned hi = (unsigned)f2bf(e2) | ((unsigned)f2bf(e3) << 16);
        uint2 pk; pk.x = lo; pk.y = hi;
        *(uint2*)&P[wave][tj * 16 + m16][i * 16 + quad * 4] = pk;
      }
    }
    // ---- PV: oacc += P(t,T) @ V(T,d) ----
    #pragma unroll
    for (int kh2 = 0; kh2 < 2; ++kh2) {
      s16x8 pa[4], vf[4];
      #pragma unroll
      for (int ti = 0; ti < 4; ++ti)
        pa[ti] = *(const s16x8*)&P[wave][ti * 16 + m16][kh2 * 32 + quad * 8];
      #pragma unroll
      for (int dj = 0; dj < 4; ++dj)
        vf[dj] = *(const s16x8*)(vbase + (size_t)(dj * 16 + m16) * Ss + T0 + kh2 * 32 + quad * 8);
      #pragma unroll
      for (int ti = 0; ti < 4; ++ti)
        #pragma unroll
        for (int dj = 0; dj < 4; ++dj)
          oacc[ti][dj] = __builtin_amdgcn_mfma_f32_16x16x32_bf16(pa[ti], vf[dj], oacc[ti][dj], 0, 0, 0);
    }
  }
  // ---- epilogue: attn (b, t, h*qpk*d) bf16 ----
  u16* abase = attn + (size_t)b * Ss * NQ + (h * QPK + qk) * HD;
  #pragma unroll
  for (int ti = 0; ti < 4; ++ti)
    #pragma unroll
    for (int dj = 0; dj < 4; ++dj)
      #pragma unroll
      for (int r = 0; r < 4; ++r)
        abase[(size_t)(t0w + ti * 16 + quad * 4 + r) * NQ + dj * 16 + m16] = f2bf(oacc[ti][dj][r]);
}

// ---------------------------------------------------------------------------
extern "C" void kernel_launch(void* const* d_in, const int* in_sizes, int n_in,
                              void* d_out, int out_size, void* d_ws, size_t ws_size,
                              hipStream_t stream)
{
  (void)in_sizes; (void)n_in; (void)out_size; (void)ws_size;
  const float* x   = (const float*)d_in[0];
  const float* lng = (const float*)d_in[1];
  const float* lnb = (const float*)d_in[2];
  const float* Wq  = (const float*)d_in[3];
  const float* bq  = (const float*)d_in[4];
  const float* Wk  = (const float*)d_in[5];
  const float* bk  = (const float*)d_in[6];
  const float* Wv  = (const float*)d_in[7];
  const float* bv  = (const float*)d_in[8];
  const float* Wo  = (const float*)d_in[9];
  const float* bo  = (const float*)d_in[10];
  float* out = (float*)d_out;

  char* ws = (char*)d_ws;
  size_t off = 0;
  auto take = [&](size_t bytes) -> char* {
    char* p = ws + off;
    off += (bytes + 255) & ~(size_t)255;
    return p;
  };
  u16*    xnb   = (u16*)take((size_t)MR * Dd * 2);           // 16 MB
  u16*    wqT   = (u16*)take((size_t)NQ * Dd * 2);           // 8 MB
  u16*    wkT   = (u16*)take((size_t)NKV * Dd * 2);          // 2 MB
  u16*    wvT   = (u16*)take((size_t)NKV * Dd * 2);          // 2 MB
  u16*    woT   = (u16*)take((size_t)Dd * NQ * 2);           // 8 MB
  u16*    qbB   = (u16*)take((size_t)MR * NQ * 2);           // 16 MB
  u16*    kbB   = (u16*)take((size_t)MR * NKV * 2);          // 4 MB
  u16*    vbB   = (u16*)take((size_t)MR * NKV * 2);          // 4 MB
  u16*    vTb   = (u16*)take((size_t)MR * NKV * 2);          // 4 MB
  float2* ml    = (float2*)take((size_t)Bb * HKV * QPK * Ss * 8); // 1 MB
  u16*    attnb = (u16*)take((size_t)MR * NQ * 2);           // 16 MB
  // ~81 MB total

  ln_kernel<<<MR, 256, 0, stream>>>(x, lng, lnb, xnb);
  transpose_cast<<<dim3(NQ / 32, Dd / 32), 256, 0, stream>>>(Wq, wqT, Dd, NQ);
  transpose_cast<<<dim3(NKV / 32, Dd / 32), 256, 0, stream>>>(Wk, wkT, Dd, NKV);
  transpose_cast<<<dim3(NKV / 32, Dd / 32), 256, 0, stream>>>(Wv, wvT, Dd, NKV);
  transpose_cast<<<dim3(NQ / 32, Dd / 32), 256, 0, stream>>>(Wo, woT, Dd, NQ);

  gemm_bt<true><<<dim3(NQ / 128, MR / 128), 256, 0, stream>>>(xnb, wqT, bq, qbB, MR, NQ, Dd, 0.125f);
  gemm_bt<true><<<dim3(NKV / 128, MR / 128), 256, 0, stream>>>(xnb, wkT, bk, kbB, MR, NKV, Dd, 1.0f);
  gemm_bt<true><<<dim3(NKV / 128, MR / 128), 256, 0, stream>>>(xnb, wvT, bv, vbB, MR, NKV, Dd, 1.0f);
  transpose_v<<<dim3(NKV / 32, MR / 32), 256, 0, stream>>>(vbB, vTb);

  pass_a_mfma<<<dim3(Ss / 256, QPK, Bb * HKV), 256, 0, stream>>>(qbB, kbB, ml);
  pass_b_mfma<<<dim3(Ss / 256, QPK, Bb * HKV), 256, 0, stream>>>(qbB, kbB, vTb, ml, attnb);

  gemm_bt<false><<<dim3(Dd / 128, MR / 128), 256, 0, stream>>>(attnb, woT, bo, out, MR, Dd, NQ, 1.0f);
}

// Round 3
// 493.016 us; speedup vs baseline: 8.3989x; 1.2398x over previous
//
#include <hip/hip_runtime.h>

// Problem constants (fixed by the reference)
#define Bb  2
#define Ss  2048
#define Dd  2048
#define HKV 8
#define QPK 4
#define HD  64
#define MR  (Bb * Ss)   // 4096 token rows
#define NQ  2048        // HQ*HD
#define NKV 512         // HKV*HD

#define LOG2E 1.4426950408889634f

typedef unsigned short u16;
typedef __attribute__((ext_vector_type(8))) short s16x8;   // 8 x bf16 (4 VGPRs)
typedef __attribute__((ext_vector_type(4))) float f32x4;   // MFMA accumulator

__device__ __forceinline__ u16 f2bf(float f) {
  unsigned u = __float_as_uint(f);
  u += 0x7fffu + ((u >> 16) & 1u);   // RNE; inputs finite
  return (u16)(u >> 16);
}

// ---------------------------------------------------------------------------
// LayerNorm: one block per row, fp32 in -> bf16 out
// ---------------------------------------------------------------------------
__global__ __launch_bounds__(256) void ln_kernel(
    const float* __restrict__ x, const float* __restrict__ g,
    const float* __restrict__ be, u16* __restrict__ xn)
{
  int row = blockIdx.x;
  int tid = threadIdx.x;
  const float4* xr = (const float4*)(x + (size_t)row * Dd);
  float4 a = xr[tid];
  float4 b4 = xr[tid + 256];
  float s  = a.x + a.y + a.z + a.w + b4.x + b4.y + b4.z + b4.w;
  float ss = a.x*a.x + a.y*a.y + a.z*a.z + a.w*a.w
           + b4.x*b4.x + b4.y*b4.y + b4.z*b4.z + b4.w*b4.w;
  #pragma unroll
  for (int off = 32; off > 0; off >>= 1) {
    s  += __shfl_down(s, off);
    ss += __shfl_down(ss, off);
  }
  __shared__ float red[8];
  int lane = tid & 63, w = tid >> 6;
  if (lane == 0) { red[w] = s; red[4 + w] = ss; }
  __syncthreads();
  s  = red[0] + red[1] + red[2] + red[3];
  ss = red[4] + red[5] + red[6] + red[7];
  float mu = s * (1.0f / Dd);
  float rs = rsqrtf(ss * (1.0f / Dd) - mu * mu + 1e-5f);

  u16* xo = xn + (size_t)row * Dd;
  const float4* gv4 = (const float4*)g;
  const float4* bv4 = (const float4*)be;
  #pragma unroll
  for (int p = 0; p < 2; ++p) {
    int idx = tid + p * 256;
    float4 xv = (p == 0) ? a : b4;
    float4 gg = gv4[idx], bb = bv4[idx];
    ushort4 pk;
    pk.x = f2bf((xv.x - mu) * rs * gg.x + bb.x);
    pk.y = f2bf((xv.y - mu) * rs * gg.y + bb.y);
    pk.z = f2bf((xv.z - mu) * rs * gg.z + bb.z);
    pk.w = f2bf((xv.w - mu) * rs * gg.w + bb.w);
    *(ushort4*)(xo + idx * 4) = pk;
  }
}

// ---------------------------------------------------------------------------
// Weight transpose + cast: W (K x N) fp32 -> WT (N x K) bf16
// ---------------------------------------------------------------------------
__global__ __launch_bounds__(256) void transpose_cast(
    const float* __restrict__ W, u16* __restrict__ WT, int K, int N)
{
  __shared__ float tile[32][33];
  int tx = threadIdx.x & 31, ty = threadIdx.x >> 5;  // ty 0..7
  int n0 = blockIdx.x * 32, k0 = blockIdx.y * 32;
  #pragma unroll
  for (int i = 0; i < 4; ++i)
    tile[ty + 8 * i][tx] = W[(size_t)(k0 + ty + 8 * i) * N + n0 + tx];
  __syncthreads();
  #pragma unroll
  for (int i = 0; i < 4; ++i)
    WT[(size_t)(n0 + ty + 8 * i) * K + k0 + tx] = f2bf(tile[tx][ty + 8 * i]);
}

// ---------------------------------------------------------------------------
// V transpose: vb (b,t, h*64+d) bf16 -> vT (b*512 + h*64+d, t) bf16
// ---------------------------------------------------------------------------
__global__ __launch_bounds__(256) void transpose_v(
    const u16* __restrict__ vb, u16* __restrict__ vT)
{
  __shared__ u16 tile[32][33];
  int tx = threadIdx.x & 31, ty = threadIdx.x >> 5;
  int c0 = blockIdx.x * 32;     // 0..511  (h*64+d)
  int r0 = blockIdx.y * 32;     // 0..4095 (b*2048+t), tiles never cross b
  #pragma unroll
  for (int i = 0; i < 4; ++i)
    tile[ty + 8 * i][tx] = vb[(size_t)(r0 + ty + 8 * i) * NKV + c0 + tx];
  __syncthreads();
  int b = r0 >> 11, t = r0 & 2047;
  #pragma unroll
  for (int i = 0; i < 4; ++i)
    vT[((size_t)(b * NKV + c0 + ty + 8 * i)) * Ss + t + tx] = tile[tx][ty + 8 * i];
}

// ---------------------------------------------------------------------------
// bf16 MFMA GEMM: C(M,N) = (A(M,K)bf16 @ BT(N,K)^T + bias) * scale
// 128x128 tile, BK=32; output fp32 or bf16
// ---------------------------------------------------------------------------
template<bool BF16OUT>
__global__ __launch_bounds__(256) void gemm_bt(
    const u16* __restrict__ A, const u16* __restrict__ BT,
    const float* __restrict__ bias, void* __restrict__ Cv,
    int M, int N, int K, float scale)
{
  __shared__ u16 As[128][40];
  __shared__ u16 Bs[128][40];
  int tid  = threadIdx.x;
  int lane = tid & 63, wave = tid >> 6;
  int wm = (wave >> 1) * 64, wn = (wave & 1) * 64;
  int m16 = lane & 15, quad = lane >> 4;
  int ar = tid >> 2;
  int ac = (tid & 3) * 8;
  const u16* Ag = A  + (size_t)(blockIdx.y * 128 + ar) * K + ac;
  const u16* Bg = BT + (size_t)(blockIdx.x * 128 + ar) * K + ac;

  f32x4 acc[4][4] = {};
  for (int k0 = 0; k0 < K; k0 += 32) {
    int4 a0 = *(const int4*)(Ag + k0);
    int4 a1 = *(const int4*)(Ag + (size_t)64 * K + k0);
    int4 b0 = *(const int4*)(Bg + k0);
    int4 b1 = *(const int4*)(Bg + (size_t)64 * K + k0);
    __syncthreads();
    *(int4*)&As[ar][ac]      = a0;
    *(int4*)&As[ar + 64][ac] = a1;
    *(int4*)&Bs[ar][ac]      = b0;
    *(int4*)&Bs[ar + 64][ac] = b1;
    __syncthreads();
    s16x8 af[4], bf[4];
    #pragma unroll
    for (int i = 0; i < 4; ++i)
      af[i] = *(const s16x8*)&As[wm + i * 16 + m16][quad * 8];
    #pragma unroll
    for (int j = 0; j < 4; ++j)
      bf[j] = *(const s16x8*)&Bs[wn + j * 16 + m16][quad * 8];
    #pragma unroll
    for (int i = 0; i < 4; ++i)
      #pragma unroll
      for (int j = 0; j < 4; ++j)
        acc[i][j] = __builtin_amdgcn_mfma_f32_16x16x32_bf16(af[i], bf[j], acc[i][j], 0, 0, 0);
  }
  #pragma unroll
  for (int i = 0; i < 4; ++i) {
    #pragma unroll
    for (int j = 0; j < 4; ++j) {
      int col = blockIdx.x * 128 + wn + j * 16 + m16;
      float bcol = bias[col];
      #pragma unroll
      for (int r = 0; r < 4; ++r) {
        int rowg = blockIdx.y * 128 + wm + i * 16 + quad * 4 + r;
        float val = (acc[i][j][r] + bcol) * scale;
        if constexpr (BF16OUT)
          ((u16*)Cv)[(size_t)rowg * N + col] = f2bf(val);
        else
          ((float*)Cv)[(size_t)rowg * N + col] = val;
      }
    }
  }
}

// ---------------------------------------------------------------------------
// Pass A: per-column softmax stats over the QUERY axis (base-2 domain).
// Block = 128 T-cols (4 waves x 32); Q t-blocks (64x64) staged in LDS and
// shared by all waves.  Per-slot online (m,l) in registers; one cross-quad
// shuffle merge at the end.  Writes c[T] = m2 + log2(l).
// Grid (64 combos, 16 g); g=0 (longest) dispatches first.
// ---------------------------------------------------------------------------
__global__ __launch_bounds__(256) void pass_a_mfma(
    const u16* __restrict__ qb, const u16* __restrict__ kb,
    float* __restrict__ cst)
{
  __shared__ u16 Qs[64][70];   // stride 35 dwords: bank = 3*m16+4*quad, depth<=2
  int combo = blockIdx.x;
  int qk = combo & 3, bh = combo >> 2;
  int b = bh >> 3, h = bh & 7;
  int g = blockIdx.y;                     // 0..15, longest first
  int tid = threadIdx.x;
  int lane = tid & 63, wave = tid >> 6;
  int m16 = lane & 15, quad = lane >> 4;
  int T0w = g * 128 + wave * 32;          // wave's 32 T-columns

  const u16* kbase = kb + (size_t)b * Ss * NKV + h * HD;
  const u16* qbase = qb + (size_t)b * Ss * NQ + (h * QPK + qk) * HD;

  s16x8 kf[2][2];   // B-operand frags (n=T), loaded once
  #pragma unroll
  for (int jg = 0; jg < 2; ++jg)
    #pragma unroll
    for (int kh = 0; kh < 2; ++kh)
      kf[jg][kh] = *(const s16x8*)(kbase + (size_t)(T0w + jg * 16 + m16) * NKV + kh * 32 + quad * 8);

  float ms[2] = {-1e30f, -1e30f};
  float ls[2] = {0.f, 0.f};
  int sr = tid >> 3, sc = (tid & 7) * 8;
  int tDiag = T0w & ~63;

  for (int t0 = g * 128; t0 < Ss; t0 += 64) {
    __syncthreads();
    *(int4*)&Qs[sr][sc]      = *(const int4*)(qbase + (size_t)(t0 + sr) * NQ + sc);
    *(int4*)&Qs[sr + 32][sc] = *(const int4*)(qbase + (size_t)(t0 + sr + 32) * NQ + sc);
    __syncthreads();
    if (t0 + 63 < T0w) continue;   // wave not yet active (barriers already done)

    s16x8 af[4][2];
    #pragma unroll
    for (int i = 0; i < 4; ++i) {
      af[i][0] = *(const s16x8*)&Qs[i * 16 + m16][quad * 8];
      af[i][1] = *(const s16x8*)&Qs[i * 16 + m16][32 + quad * 8];
    }
    f32x4 acc[4][2];
    #pragma unroll
    for (int i = 0; i < 4; ++i)
      #pragma unroll
      for (int jg = 0; jg < 2; ++jg) {
        f32x4 z = {};
        z = __builtin_amdgcn_mfma_f32_16x16x32_bf16(af[i][0], kf[jg][0], z, 0, 0, 0);
        acc[i][jg] = __builtin_amdgcn_mfma_f32_16x16x32_bf16(af[i][1], kf[jg][1], z, 0, 0, 0);
      }
    if (t0 == tDiag) {   // diagonal block: mask t < T with very-low sentinel
      #pragma unroll
      for (int i = 0; i < 4; ++i)
        #pragma unroll
        for (int jg = 0; jg < 2; ++jg) {
          int tg = t0 + i * 16 + quad * 4;
          int Tg = T0w + jg * 16 + m16;
          #pragma unroll
          for (int r = 0; r < 4; ++r)
            if (tg + r < Tg) acc[i][jg][r] = -3e38f;
        }
    }
    #pragma unroll
    for (int jg = 0; jg < 2; ++jg) {
      float bm = -3e38f;
      #pragma unroll
      for (int i = 0; i < 4; ++i)
        #pragma unroll
        for (int r = 0; r < 4; ++r) bm = fmaxf(bm, acc[i][jg][r]);
      float mn = fmaxf(ms[jg], bm);
      float se = 0.f;
      #pragma unroll
      for (int i = 0; i < 4; ++i)
        #pragma unroll
        for (int r = 0; r < 4; ++r) se += exp2f(acc[i][jg][r] - mn);
      ls[jg] = ls[jg] * exp2f(ms[jg] - mn) + se;
      ms[jg] = mn;
    }
  }
  // cross-quad merge (cols live on m16; quads hold disjoint t-subsets)
  #pragma unroll
  for (int jg = 0; jg < 2; ++jg) {
    float m = ms[jg], l = ls[jg];
    #pragma unroll
    for (int off = 16; off <= 32; off <<= 1) {
      float mo = __shfl_xor(m, off);
      float lo = __shfl_xor(l, off);
      float mn = fmaxf(m, mo);
      l = l * exp2f(m - mn) + lo * exp2f(mo - mn);
      m = mn;
    }
    if (quad == 0)
      cst[(size_t)(bh * QPK + qk) * Ss + T0w + jg * 16 + m16] = m + __log2f(l);
  }
}

// ---------------------------------------------------------------------------
// Pass B: out[t,:] = sum_{T<=t} exp2(s2(t,T)-c[T]) * v[T,:]
// Block = 64 t-rows (4 waves x 16); all 4 waves share the same T-loop length.
// K/V T-blocks staged in LDS per iter; P round-trips through per-wave LDS.
// Grid (64 combos, 32 g) with g reversed: longest blocks dispatch first.
// ---------------------------------------------------------------------------
__global__ __launch_bounds__(256) void pass_b_mfma(
    const u16* __restrict__ qb, const u16* __restrict__ kb,
    const u16* __restrict__ vT, const float* __restrict__ cst,
    u16* __restrict__ attn)
{
  __shared__ u16 Ks[64][70];
  __shared__ u16 Vs[64][70];
  __shared__ u16 P[4][16][70];
  int combo = blockIdx.x;
  int qk = combo & 3, bh = combo >> 2;
  int b = bh >> 3, h = bh & 7;
  int g = 31 - blockIdx.y;                // longest first
  int tid = threadIdx.x;
  int lane = tid & 63, wave = tid >> 6;
  int m16 = lane & 15, quad = lane >> 4;
  int trow = g * 64 + wave * 16;          // wave's 16 t-rows

  const u16* qbase = qb + (size_t)b * Ss * NQ + (h * QPK + qk) * HD;
  const u16* kbase = kb + (size_t)b * Ss * NKV + h * HD;
  const u16* vbase = vT + (size_t)(bh * 64) * Ss;
  const float* cbase = cst + (size_t)(bh * QPK + qk) * Ss;

  s16x8 qf[2];   // B-operand (n=t) frags for this wave's rows
  #pragma unroll
  for (int kh = 0; kh < 2; ++kh)
    qf[kh] = *(const s16x8*)(qbase + (size_t)(trow + m16) * NQ + kh * 32 + quad * 8);

  f32x4 oacc[4] = {};   // C-layout: row t = quad*4+r, col d = dj*16+m16
  int sr = tid >> 3, sc = (tid & 7) * 8;
  int Tend = g * 64;

  for (int T0 = 0; T0 <= Tend; T0 += 64) {
    __syncthreads();
    *(int4*)&Ks[sr][sc]      = *(const int4*)(kbase + (size_t)(T0 + sr) * NKV + sc);
    *(int4*)&Ks[sr + 32][sc] = *(const int4*)(kbase + (size_t)(T0 + sr + 32) * NKV + sc);
    *(int4*)&Vs[sr][sc]      = *(const int4*)(vbase + (size_t)sr * Ss + T0 + sc);
    *(int4*)&Vs[sr + 32][sc] = *(const int4*)(vbase + (size_t)(sr + 32) * Ss + T0 + sc);
    __syncthreads();
    bool diag = (T0 == Tend);
    // ---- scores S^T (m=T, n=t) -> normalized P (bf16) in LDS ----
    #pragma unroll
    for (int i = 0; i < 4; ++i) {
      s16x8 k0 = *(const s16x8*)&Ks[i * 16 + m16][quad * 8];
      s16x8 k1 = *(const s16x8*)&Ks[i * 16 + m16][32 + quad * 8];
      f32x4 z = {};
      z = __builtin_amdgcn_mfma_f32_16x16x32_bf16(k0, qf[0], z, 0, 0, 0);
      z = __builtin_amdgcn_mfma_f32_16x16x32_bf16(k1, qf[1], z, 0, 0, 0);
      float4 cc = *(const float4*)(cbase + T0 + i * 16 + quad * 4);
      float w0 = exp2f(z[0] - cc.x);
      float w1 = exp2f(z[1] - cc.y);
      float w2 = exp2f(z[2] - cc.z);
      float w3 = exp2f(z[3] - cc.w);
      if (diag) {
        int t  = trow + m16;
        int Tg = T0 + i * 16 + quad * 4;
        if (Tg + 0 > t) w0 = 0.f;
        if (Tg + 1 > t) w1 = 0.f;
        if (Tg + 2 > t) w2 = 0.f;
        if (Tg + 3 > t) w3 = 0.f;
      }
      unsigned u0 = __float_as_uint(w0) + 0x8000u;
      unsigned u1 = __float_as_uint(w1) + 0x8000u;
      unsigned u2 = __float_as_uint(w2) + 0x8000u;
      unsigned u3 = __float_as_uint(w3) + 0x8000u;
      uint2 pk;
      pk.x = (u0 >> 16) | (u1 & 0xffff0000u);
      pk.y = (u2 >> 16) | (u3 & 0xffff0000u);
      *(uint2*)&P[wave][m16][i * 16 + quad * 4] = pk;
    }
    // ---- PV: oacc += P(t,T) @ V(T,d)^T ----
    #pragma unroll
    for (int kh = 0; kh < 2; ++kh) {
      s16x8 pa = *(const s16x8*)&P[wave][m16][kh * 32 + quad * 8];
      #pragma unroll
      for (int dj = 0; dj < 4; ++dj) {
        s16x8 vf = *(const s16x8*)&Vs[dj * 16 + m16][kh * 32 + quad * 8];
        oacc[dj] = __builtin_amdgcn_mfma_f32_16x16x32_bf16(pa, vf, oacc[dj], 0, 0, 0);
      }
    }
  }
  // ---- epilogue: attn (b, t, (h*QPK+qk)*64 + d) bf16 ----
  u16* abase = attn + (size_t)b * Ss * NQ + (h * QPK + qk) * HD;
  #pragma unroll
  for (int dj = 0; dj < 4; ++dj)
    #pragma unroll
    for (int r = 0; r < 4; ++r)
      abase[(size_t)(trow + quad * 4 + r) * NQ + dj * 16 + m16] = f2bf(oacc[dj][r]);
}

// ---------------------------------------------------------------------------
extern "C" void kernel_launch(void* const* d_in, const int* in_sizes, int n_in,
                              void* d_out, int out_size, void* d_ws, size_t ws_size,
                              hipStream_t stream)
{
  (void)in_sizes; (void)n_in; (void)out_size; (void)ws_size;
  const float* x   = (const float*)d_in[0];
  const float* lng = (const float*)d_in[1];
  const float* lnb = (const float*)d_in[2];
  const float* Wq  = (const float*)d_in[3];
  const float* bq  = (const float*)d_in[4];
  const float* Wk  = (const float*)d_in[5];
  const float* bk  = (const float*)d_in[6];
  const float* Wv  = (const float*)d_in[7];
  const float* bv  = (const float*)d_in[8];
  const float* Wo  = (const float*)d_in[9];
  const float* bo  = (const float*)d_in[10];
  float* out = (float*)d_out;

  char* ws = (char*)d_ws;
  size_t off = 0;
  auto take = [&](size_t bytes) -> char* {
    char* p = ws + off;
    off += (bytes + 255) & ~(size_t)255;
    return p;
  };
  u16*    xnb   = (u16*)take((size_t)MR * Dd * 2);           // 16 MB
  u16*    wqT   = (u16*)take((size_t)NQ * Dd * 2);           // 8 MB
  u16*    wkT   = (u16*)take((size_t)NKV * Dd * 2);          // 2 MB
  u16*    wvT   = (u16*)take((size_t)NKV * Dd * 2);          // 2 MB
  u16*    woT   = (u16*)take((size_t)Dd * NQ * 2);           // 8 MB
  u16*    qbB   = (u16*)take((size_t)MR * NQ * 2);           // 16 MB
  u16*    kbB   = (u16*)take((size_t)MR * NKV * 2);          // 4 MB
  u16*    vbB   = (u16*)take((size_t)MR * NKV * 2);          // 4 MB
  u16*    vTb   = (u16*)take((size_t)MR * NKV * 2);          // 4 MB
  float*  cst   = (float*)take((size_t)Bb * HKV * QPK * Ss * 4); // 0.5 MB
  u16*    attnb = (u16*)take((size_t)MR * NQ * 2);           // 16 MB

  ln_kernel<<<MR, 256, 0, stream>>>(x, lng, lnb, xnb);
  transpose_cast<<<dim3(NQ / 32, Dd / 32), 256, 0, stream>>>(Wq, wqT, Dd, NQ);
  transpose_cast<<<dim3(NKV / 32, Dd / 32), 256, 0, stream>>>(Wk, wkT, Dd, NKV);
  transpose_cast<<<dim3(NKV / 32, Dd / 32), 256, 0, stream>>>(Wv, wvT, Dd, NKV);
  transpose_cast<<<dim3(NQ / 32, Dd / 32), 256, 0, stream>>>(Wo, woT, Dd, NQ);

  // q pre-scaled by 1/sqrt(HD) * log2(e): scores land in base-2 domain
  gemm_bt<true><<<dim3(NQ / 128, MR / 128), 256, 0, stream>>>(xnb, wqT, bq, qbB, MR, NQ, Dd, 0.125f * LOG2E);
  gemm_bt<true><<<dim3(NKV / 128, MR / 128), 256, 0, stream>>>(xnb, wkT, bk, kbB, MR, NKV, Dd, 1.0f);
  gemm_bt<true><<<dim3(NKV / 128, MR / 128), 256, 0, stream>>>(xnb, wvT, bv, vbB, MR, NKV, Dd, 1.0f);
  transpose_v<<<dim3(NKV / 32, MR / 32), 256, 0, stream>>>(vbB, vTb);

  pass_a_mfma<<<dim3(64, 16), 256, 0, stream>>>(qbB, kbB, cst);
  pass_b_mfma<<<dim3(64, 32), 256, 0, stream>>>(qbB, kbB, vTb, cst, attnb);

  gemm_bt<false><<<dim3(Dd / 128, MR / 128), 256, 0, stream>>>(attnb, woT, bo, out, MR, Dd, NQ, 1.0f);
}